// Round 3
// baseline (149.101 us; speedup 1.0000x reference)
//
#include <hip/hip_runtime.h>
#include <hip/hip_bf16.h>

typedef __bf16 bf16x8 __attribute__((ext_vector_type(8)));
typedef float  f32x4  __attribute__((ext_vector_type(4)));

#define LRELU_ALPHA 0.2f
#define LOG2E 1.44269504088896340736f

__device__ __forceinline__ float lrelu(float x) { return fmaxf(x, LRELU_ALPHA * x); }

__device__ __forceinline__ float fexp2(float x) {
#if __has_builtin(__builtin_amdgcn_exp2f)
    return __builtin_amdgcn_exp2f(x);
#else
    return exp2f(x);
#endif
}

// ---------------------------------------------------------------------------
// Kernel 1: h = inp @ W (8 rows per block, 128 threads), f1 = log2e*(h·a1),
// f2 = log2e*(h·a2). h kept fp32 for the residual path.
// ---------------------------------------------------------------------------
__global__ __launch_bounds__(128) void gat_prep(
    const float* __restrict__ inp, const float* __restrict__ W,
    const float* __restrict__ a,
    float* __restrict__ h, float* __restrict__ f1, float* __restrict__ f2)
{
    const int r0 = blockIdx.x << 3;      // 2048 blocks * 8 rows
    const int d  = threadIdx.x;          // 0..127
    __shared__ float sIn[8][128];
    __shared__ float sRed[8][4];
    #pragma unroll
    for (int r = 0; r < 8; ++r)
        sIn[r][d] = inp[(size_t)(r0 + r) * 128 + d];
    __syncthreads();

    float acc[8] = {0.f,0.f,0.f,0.f,0.f,0.f,0.f,0.f};
    #pragma unroll 4
    for (int k = 0; k < 128; ++k) {
        float wv = W[k * 128 + d];
        #pragma unroll
        for (int r = 0; r < 8; ++r) acc[r] += sIn[r][k] * wv;
    }

    const float a1 = a[d], a2 = a[128 + d];
    const int wv = d >> 6;
    #pragma unroll
    for (int r = 0; r < 8; ++r) {
        h[(size_t)(r0 + r) * 128 + d] = acc[r];
        float t1 = acc[r] * a1;
        float t2 = acc[r] * a2;
        #pragma unroll
        for (int m = 1; m < 64; m <<= 1) {
            t1 += __shfl_xor(t1, m);
            t2 += __shfl_xor(t2, m);
        }
        if ((d & 63) == 0) { sRed[r][wv] = t1; sRed[r][2 + wv] = t2; }
    }
    __syncthreads();
    if (d < 8) {
        f1[r0 + d] = (sRed[d][0] + sRed[d][1]) * LOG2E;
        f2[r0 + d] = (sRed[d][2] + sRed[d][3]) * LOG2E;
    }
}

// ---------------------------------------------------------------------------
// Kernel 2: per-batch max of (prescaled) f1 — exact softmax stabilizer bound
// ---------------------------------------------------------------------------
__global__ __launch_bounds__(256) void gat_f1max(
    const float* __restrict__ f1, float* __restrict__ f1max)
{
    const int b = blockIdx.x;
    const int t = threadIdx.x;
    float m = -1e30f;
    for (int j = t; j < 2048; j += 256) m = fmaxf(m, f1[b * 2048 + j]);
    #pragma unroll
    for (int k = 1; k < 64; k <<= 1) m = fmaxf(m, __shfl_xor(m, k));
    __shared__ float sm[4];
    if ((t & 63) == 0) sm[t >> 6] = m;
    __syncthreads();
    if (t == 0) f1max[b] = fmaxf(fmaxf(sm[0], sm[1]), fmaxf(sm[2], sm[3]));
}

// ---------------------------------------------------------------------------
// Kernel 3: transpose h (fp32, [b][n][128]) -> hT (bf16, [b][128][2048])
// ---------------------------------------------------------------------------
__global__ __launch_bounds__(256) void gat_transpose(
    const float* __restrict__ h, __bf16* __restrict__ hT)
{
    __shared__ __bf16 tile[64][72];      // padded
    const int tid = threadIdx.x;
    const int bidx = blockIdx.x;         // 512 blocks
    const int b  = bidx >> 6;
    const int tI = bidx & 63;
    const int n0 = (tI >> 1) << 6;
    const int d0 = (tI & 1) << 6;
    #pragma unroll
    for (int pass = 0; pass < 2; ++pass) {
        int row = (tid >> 3) + (pass << 5);
        int c   = (tid & 7) << 3;
        const float* src = h + (size_t)(b * 2048 + n0 + row) * 128 + d0 + c;
        float4 v0 = *(const float4*)src;
        float4 v1 = *(const float4*)(src + 4);
        __bf16* tp = &tile[row][c];
        tp[0]=(__bf16)v0.x; tp[1]=(__bf16)v0.y; tp[2]=(__bf16)v0.z; tp[3]=(__bf16)v0.w;
        tp[4]=(__bf16)v1.x; tp[5]=(__bf16)v1.y; tp[6]=(__bf16)v1.z; tp[7]=(__bf16)v1.w;
    }
    __syncthreads();
    #pragma unroll
    for (int pass = 0; pass < 2; ++pass) {
        int dd = (tid >> 3) + (pass << 5);
        int nn = (tid & 7) << 3;
        union { __bf16 e[8]; bf16x8 v; } u;
        #pragma unroll
        for (int x = 0; x < 8; ++x) u.e[x] = tile[nn + x][dd];
        *(bf16x8*)(hT + ((size_t)(b * 128 + d0 + dd) << 11) + n0 + nn) = u.v;
    }
}

// ---------------------------------------------------------------------------
// Kernel 4 v3: barrier-free fused attention, 8 waves/block (2 ig x 4 dq).
// Each wave: 16 i-rows x 32 d-cols. Lane computes the 8 P values of its own
// A-fragment; denominator = extra MFMA vs ones-B (bit-exact with numerator).
// Occupancy target: 2 blocks/CU = 16 waves/CU (VGPR <= 128).
// ---------------------------------------------------------------------------

#define P1(U, IDX, AJC, FC) do {                                    \
    float _x = f2v + (FC);                                          \
    float _t = fmaxf(_x, LRELU_ALPHA * _x) - Mshift;                \
    float _tf = __builtin_fmaf(_t, (float)(AJC), -1000.0f);         \
    (U).e[IDX] = (__bf16)fexp2(_tf);                                \
} while (0)

#define PF(T, A0,A1,A2,A3, B0,B1,B2,B3) do {                        \
    const int _j0 = (T) << 6;                                       \
    A0 = *(const int4*)(ajp + _j0);                                 \
    A1 = *(const int4*)(ajp + _j0 + 4);                             \
    A2 = *(const int4*)(ajp + _j0 + 32);                            \
    A3 = *(const int4*)(ajp + _j0 + 36);                            \
    B0 = *(const bf16x8*)(hTb + _j0);                               \
    B1 = *(const bf16x8*)(hTb + _j0 + 32);                          \
    B2 = *(const bf16x8*)(hTb + (16 << 11) + _j0);                  \
    B3 = *(const bf16x8*)(hTb + (16 << 11) + _j0 + 32);             \
} while (0)

#define BODY(T, A0,A1,A2,A3, B0,B1,B2,B3) do {                      \
    const int _j0 = (T) << 6;                                       \
    float4 _fa = *(const float4*)&f1s[_j0 + kb];                    \
    float4 _fb = *(const float4*)&f1s[_j0 + kb + 4];                \
    float4 _fc = *(const float4*)&f1s[_j0 + 32 + kb];               \
    float4 _fd = *(const float4*)&f1s[_j0 + 32 + kb + 4];           \
    union { __bf16 e[8]; bf16x8 v; } _u0, _u1;                      \
    P1(_u0,0,A0.x,_fa.x); P1(_u0,1,A0.y,_fa.y);                     \
    P1(_u0,2,A0.z,_fa.z); P1(_u0,3,A0.w,_fa.w);                     \
    P1(_u0,4,A1.x,_fb.x); P1(_u0,5,A1.y,_fb.y);                     \
    P1(_u0,6,A1.z,_fb.z); P1(_u0,7,A1.w,_fb.w);                     \
    P1(_u1,0,A2.x,_fc.x); P1(_u1,1,A2.y,_fc.y);                     \
    P1(_u1,2,A2.z,_fc.z); P1(_u1,3,A2.w,_fc.w);                     \
    P1(_u1,4,A3.x,_fd.x); P1(_u1,5,A3.y,_fd.y);                     \
    P1(_u1,6,A3.z,_fd.z); P1(_u1,7,A3.w,_fd.w);                     \
    acc0 = __builtin_amdgcn_mfma_f32_16x16x32_bf16(_u0.v, B0, acc0, 0,0,0); \
    acc0 = __builtin_amdgcn_mfma_f32_16x16x32_bf16(_u1.v, B1, acc0, 0,0,0); \
    acc1 = __builtin_amdgcn_mfma_f32_16x16x32_bf16(_u0.v, B2, acc1, 0,0,0); \
    acc1 = __builtin_amdgcn_mfma_f32_16x16x32_bf16(_u1.v, B3, acc1, 0,0,0); \
    accd = __builtin_amdgcn_mfma_f32_16x16x32_bf16(_u0.v, onesv, accd, 0,0,0); \
    accd = __builtin_amdgcn_mfma_f32_16x16x32_bf16(_u1.v, onesv, accd, 0,0,0); \
} while (0)

__global__ __launch_bounds__(512, 4) void gat_attn3(
    const int* __restrict__ adj, const float* __restrict__ h,
    const __bf16* __restrict__ hT, const float* __restrict__ f1g,
    const float* __restrict__ f2g, const float* __restrict__ f1maxg,
    float* __restrict__ out)
{
    // XCD-aware swizzle (512 % 8 == 0, bijective): batch <-> XCD
    const int bid = ((blockIdx.x & 7) << 6) | (blockIdx.x >> 3);
    const int b  = bid >> 6;
    const int i0 = (bid & 63) << 5;      // 32 i-rows per block
    const int tid  = threadIdx.x;
    const int w    = tid >> 6;           // wave 0..7
    const int lane = tid & 63;
    const int il   = lane & 15;
    const int kg   = lane >> 4;
    const int kb   = kg << 3;
    const int ig   = w & 1;              // i-group
    const int dq   = w >> 1;             // d-quarter 0..3
    const int ibase = i0 + (ig << 4);
    const int dbase = dq << 5;

    __shared__ float f1s[2048];
    for (int idx = tid; idx < 2048; idx += 512)
        f1s[idx] = f1g[b * 2048 + idx];

    const float fm  = f1maxg[b];
    const float f2v = f2g[b * 2048 + ibase + il];
    const float Mshift = lrelu(f2v + fm) - 1000.0f;  // exact bound: p <= 1

    const int*    ajp = adj + ((size_t)(b * 2048 + ibase + il) << 11) + kb;
    const __bf16* hTb = hT  + ((size_t)(b * 128  + dbase + il) << 11) + kb;

    f32x4 acc0 = {0.f,0.f,0.f,0.f}, acc1 = {0.f,0.f,0.f,0.f};
    f32x4 accd = {0.f,0.f,0.f,0.f};

    union { __bf16 e[8]; bf16x8 v; } ones;
    #pragma unroll
    for (int x = 0; x < 8; ++x) ones.e[x] = (__bf16)1.0f;
    const bf16x8 onesv = ones.v;

    int4 pa0, pa1, pa2, pa3;   bf16x8 pb0, pb1, pb2, pb3;
    int4 qa0, qa1, qa2, qa3;   bf16x8 qb0, qb1, qb2, qb3;

    PF(0, pa0,pa1,pa2,pa3, pb0,pb1,pb2,pb3);
    __syncthreads();                     // f1s ready (only barrier)

    for (int t = 0; t < 32; t += 2) {
        PF(t + 1, qa0,qa1,qa2,qa3, qb0,qb1,qb2,qb3);
        BODY(t, pa0,pa1,pa2,pa3, pb0,pb1,pb2,pb3);
        PF((t + 2) & 31, pa0,pa1,pa2,pa3, pb0,pb1,pb2,pb3);
        BODY(t + 1, qa0,qa1,qa2,qa3, qb0,qb1,qb2,qb3);
    }

    // epilogue: C row = kg*4+r (acc & den share the layout), col = il.
    #pragma unroll
    for (int r = 0; r < 4; ++r) {
        const int   row = (kg << 2) + r;
        const float den = accd[r];
        const size_t gbase = ((size_t)(b * 2048 + ibase + row) << 7) + dbase + il;
        float v, e;
        v = acc0[r] / den; e = (v > 0.f) ? v : (__expf(v) - 1.f); out[gbase]      = e + h[gbase];
        v = acc1[r] / den; e = (v > 0.f) ? v : (__expf(v) - 1.f); out[gbase + 16] = e + h[gbase + 16];
    }
}

// ---------------------------------------------------------------------------
extern "C" void kernel_launch(void* const* d_in, const int* in_sizes, int n_in,
                              void* d_out, int out_size, void* d_ws, size_t ws_size,
                              hipStream_t stream)
{
    const float* inp = (const float*)d_in[0];
    const int*   adj = (const int*)d_in[1];
    const float* W   = (const float*)d_in[2];
    const float* a   = (const float*)d_in[3];
    float* out = (float*)d_out;

    char* ws = (char*)d_ws;
    float*  h     = (float*)ws;                          // 8 MB
    __bf16* hT    = (__bf16*)(ws + 8388608);             // 4 MB
    float*  f1    = (float*)(ws + 8388608 + 4194304);    // 64 KB
    float*  f2    = (float*)(ws + 8388608 + 4194304 + 65536);
    float*  f1max = (float*)(ws + 8388608 + 4194304 + 131072);

    gat_prep<<<2048, 128, 0, stream>>>(inp, W, a, h, f1, f2);
    gat_f1max<<<8, 256, 0, stream>>>(f1, f1max);
    gat_transpose<<<512, 256, 0, stream>>>(h, hT);
    gat_attn3<<<512, 512, 0, stream>>>(adj, h, hT, f1, f2, f1max, out);
}

// Round 4
// 61.484 us; speedup vs baseline: 2.4250x; 2.4250x over previous
//
#include <hip/hip_runtime.h>
#include <hip/hip_bf16.h>

typedef __bf16 bf16x8 __attribute__((ext_vector_type(8)));
typedef __bf16 bf16x4 __attribute__((ext_vector_type(4)));
typedef float  f32x4  __attribute__((ext_vector_type(4)));

#define LRELU_ALPHA 0.2f
#define LOG2E 1.44269504088896340736f

__device__ __forceinline__ float lrelu(float x) { return fmaxf(x, LRELU_ALPHA * x); }
__device__ __forceinline__ float fexp2(float x) { return exp2f(x); }

// raw barrier: drains LDS (lgkmcnt) but leaves global prefetches (vmcnt) in flight
__device__ __forceinline__ void wg_barrier() {
    asm volatile("s_waitcnt lgkmcnt(0)" ::: "memory");
    __builtin_amdgcn_s_barrier();
    asm volatile("" ::: "memory");
}

// ---------------------------------------------------------------------------
// Kernel 1: h = inp @ W (8 rows per block), f1 = log2e*(h·a1), f2 = log2e*(h·a2)
// ---------------------------------------------------------------------------
__global__ __launch_bounds__(128) void gat_prep(
    const float* __restrict__ inp, const float* __restrict__ W,
    const float* __restrict__ a,
    float* __restrict__ h, float* __restrict__ f1, float* __restrict__ f2)
{
    const int r0 = blockIdx.x << 3;
    const int d  = threadIdx.x;
    __shared__ float sIn[8][128];
    __shared__ float sRed[8][4];
    #pragma unroll
    for (int r = 0; r < 8; ++r)
        sIn[r][d] = inp[(size_t)(r0 + r) * 128 + d];
    __syncthreads();

    float acc[8] = {0.f,0.f,0.f,0.f,0.f,0.f,0.f,0.f};
    #pragma unroll 4
    for (int k = 0; k < 128; ++k) {
        float wv = W[k * 128 + d];
        #pragma unroll
        for (int r = 0; r < 8; ++r) acc[r] += sIn[r][k] * wv;
    }

    const float a1 = a[d], a2 = a[128 + d];
    const int wv = d >> 6;
    #pragma unroll
    for (int r = 0; r < 8; ++r) {
        h[(size_t)(r0 + r) * 128 + d] = acc[r];
        float t1 = acc[r] * a1;
        float t2 = acc[r] * a2;
        #pragma unroll
        for (int m = 1; m < 64; m <<= 1) {
            t1 += __shfl_xor(t1, m);
            t2 += __shfl_xor(t2, m);
        }
        if ((d & 63) == 0) { sRed[r][wv] = t1; sRed[r][2 + wv] = t2; }
    }
    __syncthreads();
    if (d < 8) {
        f1[r0 + d] = (sRed[d][0] + sRed[d][1]) * LOG2E;
        f2[r0 + d] = (sRed[d][2] + sRed[d][3]) * LOG2E;
    }
}

// ---------------------------------------------------------------------------
// Kernel 2: per-batch max of (prescaled) f1
// ---------------------------------------------------------------------------
__global__ __launch_bounds__(256) void gat_f1max(
    const float* __restrict__ f1, float* __restrict__ f1max)
{
    const int b = blockIdx.x;
    const int t = threadIdx.x;
    float m = -1e30f;
    for (int j = t; j < 2048; j += 256) m = fmaxf(m, f1[b * 2048 + j]);
    #pragma unroll
    for (int k = 1; k < 64; k <<= 1) m = fmaxf(m, __shfl_xor(m, k));
    __shared__ float sm[4];
    if ((t & 63) == 0) sm[t >> 6] = m;
    __syncthreads();
    if (t == 0) f1max[b] = fmaxf(fmaxf(sm[0], sm[1]), fmaxf(sm[2], sm[3]));
}

// ---------------------------------------------------------------------------
// Kernel 3: transpose h (fp32 [b][n][128]) -> hT (bf16 [b][128][2048])
// ---------------------------------------------------------------------------
__global__ __launch_bounds__(256) void gat_transpose(
    const float* __restrict__ h, __bf16* __restrict__ hT)
{
    __shared__ __bf16 tile[64][72];
    const int tid = threadIdx.x;
    const int bidx = blockIdx.x;
    const int b  = bidx >> 6;
    const int tI = bidx & 63;
    const int n0 = (tI >> 1) << 6;
    const int d0 = (tI & 1) << 6;
    #pragma unroll
    for (int pass = 0; pass < 2; ++pass) {
        int row = (tid >> 3) + (pass << 5);
        int c   = (tid & 7) << 3;
        const float* src = h + (size_t)(b * 2048 + n0 + row) * 128 + d0 + c;
        float4 v0 = *(const float4*)src;
        float4 v1 = *(const float4*)(src + 4);
        __bf16* tp = &tile[row][c];
        tp[0]=(__bf16)v0.x; tp[1]=(__bf16)v0.y; tp[2]=(__bf16)v0.z; tp[3]=(__bf16)v0.w;
        tp[4]=(__bf16)v1.x; tp[5]=(__bf16)v1.y; tp[6]=(__bf16)v1.z; tp[7]=(__bf16)v1.w;
    }
    __syncthreads();
    #pragma unroll
    for (int pass = 0; pass < 2; ++pass) {
        int dd = (tid >> 3) + (pass << 5);
        int nn = (tid & 7) << 3;
        union { __bf16 e[8]; bf16x8 v; } u;
        #pragma unroll
        for (int x = 0; x < 8; ++x) u.e[x] = tile[nn + x][dd];
        *(bf16x8*)(hT + ((size_t)(b * 128 + d0 + dd) << 11) + n0 + nn) = u.v;
    }
}

// ---------------------------------------------------------------------------
// Kernel 4 v4: LDS-staged fused attention. 512 thr (8 waves), 32 i x 128 d.
// Phase A: coalesced adj->reg prefetch (2-deep) + P computed ONCE (4/thread)
//          -> swizzled LDS; hT tile reg->LDS (double-buffered, swizzled).
// Phase B: conflict-free ds_read_b128 fragments + 4 MFMA per wave.
// Raw s_barrier (lgkm-only) keeps global prefetches in flight across barriers.
// ---------------------------------------------------------------------------
#define SWZH(row, byteoff) ((byteoff) ^ (((row) & 7) << 4))

__global__ __launch_bounds__(512, 4) void gat_attn4(
    const int* __restrict__ adj, const float* __restrict__ h,
    const __bf16* __restrict__ hT, const float* __restrict__ f1g,
    const float* __restrict__ f2g, const float* __restrict__ f1maxg,
    float* __restrict__ out)
{
    const int bid = ((blockIdx.x & 7) << 6) | (blockIdx.x >> 3);  // batch<->XCD
    const int b  = bid >> 6;
    const int i0 = (bid & 63) << 5;
    const int tid = threadIdx.x;

    __shared__ float  f1s[2048];
    __shared__ alignas(16) __bf16 hTs[2][128 * 64];
    __shared__ alignas(16) __bf16 Ps[32 * 64];
    __shared__ float  lsum[32];

    // f1s init (coalesced float4)
    *(float4*)&f1s[tid << 2] = *(const float4*)&f1g[(b << 11) + (tid << 2)];

    // ---- phase-A mapping: thread -> (row pi, j-quad pj4) ----
    const int pi  = tid >> 4;
    const int pj4 = tid & 15;
    const float fm  = f1maxg[b];
    const float f2v = f2g[(b << 11) + i0 + pi];
    const float Mshift = lrelu(f2v + fm) - 1000.0f;   // exact bound: p <= 1
    const int* ajp = adj + (((size_t)(b << 11) + i0 + pi) << 11) + (pj4 << 2);
    __bf16* pw = Ps + (pi << 6) + (SWZH(pi, pj4 << 3) >> 1);

    // hT staging: thread stages rows hd0 and hd0+64, 16B j-chunk each
    const int hd0 = tid >> 3;
    const int hjc = (tid & 7) << 3;
    const __bf16* hgp0 = hT + (((size_t)(b << 7) + hd0) << 11) + hjc;
    const __bf16* hgp1 = hT + (((size_t)(b << 7) + hd0 + 64) << 11) + hjc;
    const int hw0 = (hd0 << 6) + (SWZH(hd0, hjc << 1) >> 1);
    const int hw1 = ((hd0 + 64) << 6) + (SWZH(hd0, hjc << 1) >> 1);

    // ---- phase-B mapping: wave -> (i-group, d-quarter) ----
    const int w    = tid >> 6;
    const int lane = tid & 63;
    const int il   = lane & 15;
    const int kg   = lane >> 4;
    const int ig   = w & 1;
    const int dq   = w >> 1;
    const int ai   = (ig << 4) + il;
    const int d0r  = (dq << 5) + il;
    const int d1r  = d0r + 16;
    const int aof0 = (ai << 6)  + (SWZH(ai,       kg << 4) >> 1);
    const int aof1 = (ai << 6)  + (SWZH(ai, 64 | (kg << 4)) >> 1);
    const int bof00 = (d0r << 6) + (SWZH(d0r,       kg << 4) >> 1);
    const int bof01 = (d0r << 6) + (SWZH(d0r, 64 | (kg << 4)) >> 1);
    const int bof10 = (d1r << 6) + (SWZH(d1r,       kg << 4) >> 1);
    const int bof11 = (d1r << 6) + (SWZH(d1r, 64 | (kg << 4)) >> 1);

    // ---- prologue: tile0 staged, adj 2-deep, hT 1-deep prefetch ----
    int4   gA  = *(const int4*)ajp;                  // adj tile 0
    int4   gA2 = *(const int4*)(ajp + 64);           // adj tile 1
    bf16x8 gH0 = *(const bf16x8*)hgp0;               // hT tile 0
    bf16x8 gH1 = *(const bf16x8*)hgp1;
    *(bf16x8*)(hTs[0] + hw0) = gH0;
    *(bf16x8*)(hTs[0] + hw1) = gH1;
    gH0 = *(const bf16x8*)(hgp0 + 64);               // hT tile 1
    gH1 = *(const bf16x8*)(hgp1 + 64);

    f32x4 acc0 = {0.f,0.f,0.f,0.f}, acc1 = {0.f,0.f,0.f,0.f};
    float den = 0.f;

    wg_barrier();                                    // f1s + hTs[0] ready

    for (int t = 0; t < 32; ++t) {
        // ---------------- phase A ----------------
        int4 adjv = gA;
        gA  = gA2;
        gA2 = *(const int4*)(ajp + (((t + 2) & 31) << 6));   // 2-deep

        __bf16* hb = hTs[(t + 1) & 1];               // stage tile t+1
        *(bf16x8*)(hb + hw0) = gH0;
        *(bf16x8*)(hb + hw1) = gH1;
        gH0 = *(const bf16x8*)(hgp0 + (((t + 2) & 31) << 6));
        gH1 = *(const bf16x8*)(hgp1 + (((t + 2) & 31) << 6));

        float4 fv = *(const float4*)&f1s[(t << 6) + (pj4 << 2)];
        float p0, p1, p2, p3;
        { float x = f2v + fv.x; float e = fmaxf(x, LRELU_ALPHA * x) - Mshift;
          p0 = fexp2(__builtin_fmaf(e, (float)adjv.x, -1000.f)); }
        { float x = f2v + fv.y; float e = fmaxf(x, LRELU_ALPHA * x) - Mshift;
          p1 = fexp2(__builtin_fmaf(e, (float)adjv.y, -1000.f)); }
        { float x = f2v + fv.z; float e = fmaxf(x, LRELU_ALPHA * x) - Mshift;
          p2 = fexp2(__builtin_fmaf(e, (float)adjv.z, -1000.f)); }
        { float x = f2v + fv.w; float e = fmaxf(x, LRELU_ALPHA * x) - Mshift;
          p3 = fexp2(__builtin_fmaf(e, (float)adjv.w, -1000.f)); }
        bf16x4 pb;
        pb[0] = (__bf16)p0; pb[1] = (__bf16)p1;
        pb[2] = (__bf16)p2; pb[3] = (__bf16)p3;
        den += (float)pb[0] + (float)pb[1] + (float)pb[2] + (float)pb[3];
        *(bf16x4*)pw = pb;

        wg_barrier();                                // P + hT[t+1] ready

        // ---------------- phase B ----------------
        const __bf16* hr = hTs[t & 1];
        bf16x8 A0  = *(const bf16x8*)(Ps + aof0);
        bf16x8 A1  = *(const bf16x8*)(Ps + aof1);
        bf16x8 B00 = *(const bf16x8*)(hr + bof00);
        bf16x8 B01 = *(const bf16x8*)(hr + bof01);
        bf16x8 B10 = *(const bf16x8*)(hr + bof10);
        bf16x8 B11 = *(const bf16x8*)(hr + bof11);
        acc0 = __builtin_amdgcn_mfma_f32_16x16x32_bf16(A0, B00, acc0, 0, 0, 0);
        acc0 = __builtin_amdgcn_mfma_f32_16x16x32_bf16(A1, B01, acc0, 0, 0, 0);
        acc1 = __builtin_amdgcn_mfma_f32_16x16x32_bf16(A0, B10, acc1, 0, 0, 0);
        acc1 = __builtin_amdgcn_mfma_f32_16x16x32_bf16(A1, B11, acc1, 0, 0, 0);

        wg_barrier();                                // protect Ps / hTs[t&1]
    }

    // ---- denominator: reduce over the 16 j-quad lanes of each row ----
    den += __shfl_xor(den, 1);
    den += __shfl_xor(den, 2);
    den += __shfl_xor(den, 4);
    den += __shfl_xor(den, 8);
    if (pj4 == 0) lsum[pi] = den;
    wg_barrier();

    // ---- epilogue: normalize, elu, residual ----
    #pragma unroll
    for (int r = 0; r < 4; ++r) {
        const int   row = (kg << 2) + r;
        const float dn  = lsum[(ig << 4) + row];
        const size_t gbase = (((size_t)(b << 11) + i0 + (ig << 4) + row) << 7)
                             + (dq << 5) + il;
        float v, e;
        v = acc0[r] / dn; e = (v > 0.f) ? v : (__expf(v) - 1.f); out[gbase]      = e + h[gbase];
        v = acc1[r] / dn; e = (v > 0.f) ? v : (__expf(v) - 1.f); out[gbase + 16] = e + h[gbase + 16];
    }
}

// ---------------------------------------------------------------------------
extern "C" void kernel_launch(void* const* d_in, const int* in_sizes, int n_in,
                              void* d_out, int out_size, void* d_ws, size_t ws_size,
                              hipStream_t stream)
{
    const float* inp = (const float*)d_in[0];
    const int*   adj = (const int*)d_in[1];
    const float* W   = (const float*)d_in[2];
    const float* a   = (const float*)d_in[3];
    float* out = (float*)d_out;

    char* ws = (char*)d_ws;
    float*  h     = (float*)ws;                          // 8 MB
    __bf16* hT    = (__bf16*)(ws + 8388608);             // 4 MB
    float*  f1    = (float*)(ws + 8388608 + 4194304);    // 64 KB
    float*  f2    = (float*)(ws + 8388608 + 4194304 + 65536);
    float*  f1max = (float*)(ws + 8388608 + 4194304 + 131072);

    gat_prep<<<2048, 128, 0, stream>>>(inp, W, a, h, f1, f2);
    gat_f1max<<<8, 256, 0, stream>>>(f1, f1max);
    gat_transpose<<<512, 256, 0, stream>>>(h, hT);
    gat_attn4<<<512, 512, 0, stream>>>(adj, h, hT, f1, f2, f1max, out);
}

// Round 5
// 59.600 us; speedup vs baseline: 2.5017x; 1.0316x over previous
//
#include <hip/hip_runtime.h>
#include <hip/hip_bf16.h>

typedef __bf16 bf16x8 __attribute__((ext_vector_type(8)));
typedef __bf16 bf16x4 __attribute__((ext_vector_type(4)));
typedef float  f32x4  __attribute__((ext_vector_type(4)));

#define LRELU_ALPHA 0.2f
#define LOG2E 1.44269504088896340736f

__device__ __forceinline__ float fexp2(float x) { return exp2f(x); }

// raw barrier: drains LDS (lgkmcnt) but leaves global prefetches (vmcnt) in flight
__device__ __forceinline__ void wg_barrier() {
    asm volatile("s_waitcnt lgkmcnt(0)" ::: "memory");
    __builtin_amdgcn_s_barrier();
    asm volatile("" ::: "memory");
}

// ---------------------------------------------------------------------------
// Kernel 1: h = inp @ W (8 rows per block), f1 = log2e*(h·a1), f2 = log2e*(h·a2)
// ---------------------------------------------------------------------------
__global__ __launch_bounds__(128) void gat_prep(
    const float* __restrict__ inp, const float* __restrict__ W,
    const float* __restrict__ a,
    float* __restrict__ h, float* __restrict__ f1, float* __restrict__ f2)
{
    const int r0 = blockIdx.x << 3;
    const int d  = threadIdx.x;
    __shared__ float sIn[8][128];
    __shared__ float sRed[8][4];
    #pragma unroll
    for (int r = 0; r < 8; ++r)
        sIn[r][d] = inp[(size_t)(r0 + r) * 128 + d];
    __syncthreads();

    float acc[8] = {0.f,0.f,0.f,0.f,0.f,0.f,0.f,0.f};
    #pragma unroll 4
    for (int k = 0; k < 128; ++k) {
        float wv = W[k * 128 + d];
        #pragma unroll
        for (int r = 0; r < 8; ++r) acc[r] += sIn[r][k] * wv;
    }

    const float a1 = a[d], a2 = a[128 + d];
    const int wv = d >> 6;
    #pragma unroll
    for (int r = 0; r < 8; ++r) {
        h[(size_t)(r0 + r) * 128 + d] = acc[r];
        float t1 = acc[r] * a1;
        float t2 = acc[r] * a2;
        #pragma unroll
        for (int m = 1; m < 64; m <<= 1) {
            t1 += __shfl_xor(t1, m);
            t2 += __shfl_xor(t2, m);
        }
        if ((d & 63) == 0) { sRed[r][wv] = t1; sRed[r][2 + wv] = t2; }
    }
    __syncthreads();
    if (d < 8) {
        f1[r0 + d] = (sRed[d][0] + sRed[d][1]) * LOG2E;
        f2[r0 + d] = (sRed[d][2] + sRed[d][3]) * LOG2E;
    }
}

// ---------------------------------------------------------------------------
// Kernel 2: per-batch max of (prescaled) f1
// ---------------------------------------------------------------------------
__global__ __launch_bounds__(256) void gat_f1max(
    const float* __restrict__ f1, float* __restrict__ f1max)
{
    const int b = blockIdx.x;
    const int t = threadIdx.x;
    float m = -1e30f;
    for (int j = t; j < 2048; j += 256) m = fmaxf(m, f1[b * 2048 + j]);
    #pragma unroll
    for (int k = 1; k < 64; k <<= 1) m = fmaxf(m, __shfl_xor(m, k));
    __shared__ float sm[4];
    if ((t & 63) == 0) sm[t >> 6] = m;
    __syncthreads();
    if (t == 0) f1max[b] = fmaxf(fmaxf(sm[0], sm[1]), fmaxf(sm[2], sm[3]));
}

// ---------------------------------------------------------------------------
// Kernel 3: h (fp32 [b][n][128]) -> pack: fragment-major bf16 B-operands.
// pack element offset = (b*32 + jt)*8192 + frag*512 + lane*8, frag = D*2+jh.
// Fragment lane(il,kg) holds h[jt*64 + jh*32 + kg*8 + e][D*16 + il], e=0..7.
// A wave's B-load is then base + lane*16B: fully coalesced 1KB.
// ---------------------------------------------------------------------------
__global__ __launch_bounds__(256) void gat_pack(
    const float* __restrict__ h, __bf16* __restrict__ pack)
{
    __shared__ __bf16 tile[64][74];      // pad 74: phase-2 column reads hit all 32 banks
    const int tid = threadIdx.x;
    const int bidx = blockIdx.x;         // 512 blocks
    const int b  = bidx >> 6;
    const int tI = bidx & 63;
    const int n0 = (tI >> 1) << 6;       // j-range 64
    const int d0 = (tI & 1) << 6;        // d-range 64
    #pragma unroll
    for (int pass = 0; pass < 2; ++pass) {
        int row = (tid >> 3) + (pass << 5);     // j within tile
        int c   = (tid & 7) << 3;               // d within tile
        const float* src = h + (size_t)(b * 2048 + n0 + row) * 128 + d0 + c;
        float4 v0 = *(const float4*)src;
        float4 v1 = *(const float4*)(src + 4);
        __bf16* tp = &tile[row][c];
        tp[0]=(__bf16)v0.x; tp[1]=(__bf16)v0.y; tp[2]=(__bf16)v0.z; tp[3]=(__bf16)v0.w;
        tp[4]=(__bf16)v1.x; tp[5]=(__bf16)v1.y; tp[6]=(__bf16)v1.z; tp[7]=(__bf16)v1.w;
    }
    __syncthreads();
    const int lane = tid & 63;
    const int il = lane & 15;
    const int kg = lane >> 4;
    #pragma unroll
    for (int pass = 0; pass < 2; ++pass) {
        const int f  = (tid >> 6) + (pass << 2);   // fragment 0..7 of this block
        const int Dl = f >> 1;                     // local D (16-col group)
        const int jh = f & 1;                      // j-half
        union { __bf16 e[8]; bf16x8 v; } u;
        #pragma unroll
        for (int e = 0; e < 8; ++e)
            u.e[e] = tile[(jh << 5) + (kg << 3) + e][(Dl << 4) + il];
        const size_t off = (((size_t)(b << 5) + (n0 >> 6)) << 13)
                         + ((size_t)((((d0 >> 4) + Dl) << 1) | jh) << 9)
                         + (lane << 3);
        *(bf16x8*)(pack + off) = u.v;              // coalesced 1KB per wave
    }
}

// ---------------------------------------------------------------------------
// Kernel 4 v5: fused attention. 512 thr (8 waves = 2 ig x 4 dq), 32 i x 128 d.
// B-fragments straight from global (packed, coalesced, L2-resident).
// P double-buffered in LDS; ONE barrier per iteration. adj 2-deep, B 1-deep
// register prefetch kept in flight across the lgkm-only barrier.
// ---------------------------------------------------------------------------
#define PCOMPUTE(TT, BUF) do {                                                \
    float4 fv = *(const float4*)&f1s[((TT) << 6) + (pj4 << 2)];               \
    float p0, p1, p2, p3;                                                     \
    { float x = f2v + fv.x; float e = fmaxf(x, LRELU_ALPHA * x) - Mshift;     \
      p0 = fexp2(__builtin_fmaf(e, (float)gA.x, -1000.f)); }                  \
    { float x = f2v + fv.y; float e = fmaxf(x, LRELU_ALPHA * x) - Mshift;     \
      p1 = fexp2(__builtin_fmaf(e, (float)gA.y, -1000.f)); }                  \
    { float x = f2v + fv.z; float e = fmaxf(x, LRELU_ALPHA * x) - Mshift;     \
      p2 = fexp2(__builtin_fmaf(e, (float)gA.z, -1000.f)); }                  \
    { float x = f2v + fv.w; float e = fmaxf(x, LRELU_ALPHA * x) - Mshift;     \
      p3 = fexp2(__builtin_fmaf(e, (float)gA.w, -1000.f)); }                  \
    bf16x4 pb;                                                                \
    pb[0] = (__bf16)p0; pb[1] = (__bf16)p1;                                   \
    pb[2] = (__bf16)p2; pb[3] = (__bf16)p3;                                   \
    den += (float)pb[0] + (float)pb[1] + (float)pb[2] + (float)pb[3];         \
    *(bf16x4*)(&Ps[BUF][pwo]) = pb;                                           \
} while (0)

__global__ __launch_bounds__(512, 4) void gat_attn5(
    const int* __restrict__ adj, const float* __restrict__ h,
    const __bf16* __restrict__ pack, const float* __restrict__ f1g,
    const float* __restrict__ f2g, const float* __restrict__ f1maxg,
    float* __restrict__ out)
{
    const int bid = ((blockIdx.x & 7) << 6) | (blockIdx.x >> 3);  // batch<->XCD
    const int b  = bid >> 6;
    const int i0 = (bid & 63) << 5;
    const int tid = threadIdx.x;

    __shared__ float f1s[2048];
    __shared__ alignas(16) __bf16 Ps[2][2048];   // double-buffered P (32x64)
    __shared__ float lsum[32];

    *(float4*)&f1s[tid << 2] = *(const float4*)&f1g[(b << 11) + (tid << 2)];

    // ---- phase-A mapping: thread -> (row pi, j-quad pj4) ----
    const int pi  = tid >> 4;
    const int pj4 = tid & 15;
    const float fm  = f1maxg[b];
    const float f2v = f2g[(b << 11) + i0 + pi];
    const float Mshift = fmaxf(f2v + fm, LRELU_ALPHA * (f2v + fm)) - 1000.0f;
    const int* ajp = adj + (((size_t)(b << 11) + i0 + pi) << 11) + (pj4 << 2);
    const int pwo = (pi << 6) + ((((pj4 << 3)) ^ ((pi & 7) << 4)) >> 1);

    // ---- phase-B mapping: wave -> (i-group, d-quarter) ----
    const int w    = tid >> 6;
    const int lane = tid & 63;
    const int il   = lane & 15;
    const int kg   = lane >> 4;
    const int ig   = w & 1;
    const int dq   = w >> 1;
    const int ai   = (ig << 4) + il;
    const int aof0 = (ai << 6) + (((kg << 4) ^ ((ai & 7) << 4)) >> 1);
    const int aof1 = (ai << 6) + (((64 | (kg << 4)) ^ ((ai & 7) << 4)) >> 1);
    const __bf16* pB = pack + (((size_t)b << 5) << 13) + (dq << 11) + (lane << 3);

    f32x4 acc0 = {0.f,0.f,0.f,0.f}, acc1 = {0.f,0.f,0.f,0.f};
    float den = 0.f;

    // ---- prologue ----
    int4 gA  = *(const int4*)ajp;                 // adj tile 0
    int4 gA2 = *(const int4*)(ajp + 64);          // adj tile 1
    bf16x8 Bc0 = *(const bf16x8*)(pB);            // B tile 0
    bf16x8 Bc1 = *(const bf16x8*)(pB + 512);
    bf16x8 Bc2 = *(const bf16x8*)(pB + 1024);
    bf16x8 Bc3 = *(const bf16x8*)(pB + 1536);

    wg_barrier();                                 // f1s ready

    PCOMPUTE(0, 0);                               // P(0) -> Ps[0]
    gA = gA2;
    gA2 = *(const int4*)(ajp + 128);              // adj tile 2

    wg_barrier();                                 // Ps[0] ready

    for (int t = 0; t < 31; ++t) {
        // issue B(t+1) loads (used next iter; vmcnt stays in flight)
        const __bf16* pBn = pB + ((size_t)(t + 1) << 13);
        bf16x8 Bn0 = *(const bf16x8*)(pBn);
        bf16x8 Bn1 = *(const bf16x8*)(pBn + 512);
        bf16x8 Bn2 = *(const bf16x8*)(pBn + 1024);
        bf16x8 Bn3 = *(const bf16x8*)(pBn + 1536);

        // A-fragments of tile t (written last iter, ordered by barrier)
        bf16x8 A0 = *(const bf16x8*)(&Ps[t & 1][aof0]);
        bf16x8 A1 = *(const bf16x8*)(&Ps[t & 1][aof1]);

        // P(t+1) -> other buffer; advance adj chain
        PCOMPUTE(t + 1, (t + 1) & 1);
        gA = gA2;
        gA2 = *(const int4*)(ajp + (((t + 3) & 31) << 6));

        acc0 = __builtin_amdgcn_mfma_f32_16x16x32_bf16(A0, Bc0, acc0, 0, 0, 0);
        acc0 = __builtin_amdgcn_mfma_f32_16x16x32_bf16(A1, Bc1, acc0, 0, 0, 0);
        acc1 = __builtin_amdgcn_mfma_f32_16x16x32_bf16(A0, Bc2, acc1, 0, 0, 0);
        acc1 = __builtin_amdgcn_mfma_f32_16x16x32_bf16(A1, Bc3, acc1, 0, 0, 0);

        Bc0 = Bn0; Bc1 = Bn1; Bc2 = Bn2; Bc3 = Bn3;

        wg_barrier();                             // Ps[(t+1)&1] ready / reads done
    }

    {   // peeled t = 31
        bf16x8 A0 = *(const bf16x8*)(&Ps[1][aof0]);
        bf16x8 A1 = *(const bf16x8*)(&Ps[1][aof1]);
        acc0 = __builtin_amdgcn_mfma_f32_16x16x32_bf16(A0, Bc0, acc0, 0, 0, 0);
        acc0 = __builtin_amdgcn_mfma_f32_16x16x32_bf16(A1, Bc1, acc0, 0, 0, 0);
        acc1 = __builtin_amdgcn_mfma_f32_16x16x32_bf16(A0, Bc2, acc1, 0, 0, 0);
        acc1 = __builtin_amdgcn_mfma_f32_16x16x32_bf16(A1, Bc3, acc1, 0, 0, 0);
    }

    // ---- denominator: reduce over the 16 j-quad lanes of each row ----
    den += __shfl_xor(den, 1);
    den += __shfl_xor(den, 2);
    den += __shfl_xor(den, 4);
    den += __shfl_xor(den, 8);
    if (pj4 == 0) lsum[pi] = den;
    wg_barrier();

    // ---- epilogue: normalize, elu, residual ----
    #pragma unroll
    for (int r = 0; r < 4; ++r) {
        const int   row = (kg << 2) + r;
        const float dn  = lsum[(ig << 4) + row];
        const size_t gbase = (((size_t)(b << 11) + i0 + (ig << 4) + row) << 7)
                             + (dq << 5) + il;
        float v, e;
        v = acc0[r] / dn; e = (v > 0.f) ? v : (__expf(v) - 1.f); out[gbase]      = e + h[gbase];
        v = acc1[r] / dn; e = (v > 0.f) ? v : (__expf(v) - 1.f); out[gbase + 16] = e + h[gbase + 16];
    }
}

// ---------------------------------------------------------------------------
extern "C" void kernel_launch(void* const* d_in, const int* in_sizes, int n_in,
                              void* d_out, int out_size, void* d_ws, size_t ws_size,
                              hipStream_t stream)
{
    const float* inp = (const float*)d_in[0];
    const int*   adj = (const int*)d_in[1];
    const float* W   = (const float*)d_in[2];
    const float* a   = (const float*)d_in[3];
    float* out = (float*)d_out;

    char* ws = (char*)d_ws;
    float*  h     = (float*)ws;                          // 8 MB
    __bf16* pack  = (__bf16*)(ws + 8388608);             // 4 MB (fragment-major)
    float*  f1    = (float*)(ws + 8388608 + 4194304);    // 64 KB
    float*  f2    = (float*)(ws + 8388608 + 4194304 + 65536);
    float*  f1max = (float*)(ws + 8388608 + 4194304 + 131072);

    gat_prep<<<2048, 128, 0, stream>>>(inp, W, a, h, f1, f2);
    gat_f1max<<<8, 256, 0, stream>>>(f1, f1max);
    gat_pack<<<512, 256, 0, stream>>>(h, pack);
    gat_attn5<<<512, 512, 0, stream>>>(adj, h, pack, f1, f2, f1max, out);
}